// Round 15
// baseline (268.196 us; speedup 1.0000x reference)
//
#include <hip/hip_runtime.h>
#include <math.h>

#define ALPHA 0.3f

constexpr int B  = 32;
constexpr int N  = 100;
constexpr int NF = 128;
constexpr int L  = 3;
constexpr int NN = N * N;            // 10000
constexpr int NTRI = N * (N + 1) / 2;        // 5050 pairs i<=j
constexpr int NPAIR_TRI = B * NTRI;          // 161600
constexpr int PT = 64;               // pairs per block (4 m-tiles, 2 per m-group)
constexpr int RT = 32;               // rows per block in the node MFMA MLP

typedef __attribute__((ext_vector_type(8))) short short8;
typedef __attribute__((ext_vector_type(4))) float f32x4;

__device__ __forceinline__ unsigned short f2bf(float x) {
    union { float f; unsigned u; } v; v.f = x;
    unsigned r = v.u + 0x7FFF + ((v.u >> 16) & 1);  // RNE
    return (unsigned short)(r >> 16);
}
__device__ __forceinline__ float bf2f(unsigned short h) {
    union { unsigned u; float f; } v; v.u = ((unsigned)h) << 16;
    return v.f;
}
// packed f32x2 -> bf16x2 (RNE, same rounding as f2bf)
__device__ __forceinline__ unsigned cvt_pk(float lo, float hi) {
    unsigned r;
    asm("v_cvt_pk_bf16_f32 %0, %1, %2" : "=v"(r) : "v"(lo), "v"(hi));
    return r;
}

// triangular decode: t in [0,5050) -> (i,j), j>=i (used once in table prep)
__device__ __forceinline__ void tri_decode(int t, int& io, int& jo) {
    int ii = (int)((201.0f - sqrtf(40401.0f - 8.0f * (float)t)) * 0.5f);
    ii = max(0, min(99, ii));
    while (ii > 0 && ii * (201 - ii) / 2 > t) --ii;
    while ((ii + 1) * (200 - ii) / 2 <= t) ++ii;
    io = ii;
    jo = ii + (t - ii * (201 - ii) / 2);
}

// ---------------------------------------------------------------------------
// Weight prep element, MFMA-fragment order (16x16x32), generic K,C:
// Wp[((l*CT+ct)*KS+ks)*64 + lane][8] = W[l][ks*32+(lane>>4)*8+j][ct*16+(lane&15)] * S
// ---------------------------------------------------------------------------
__device__ __forceinline__ void wprep_elem(const float* __restrict__ W,
                                           const float* __restrict__ S,
                                           unsigned short* __restrict__ Wp,
                                           int K, int C, int idx) {
    const int per = K * C;
    const int l = idx / per, r = idx - l * per;
    const int KS = K / 32;
    const int j    = r & 7;
    const int lane = (r >> 3) & 63;
    const int t2   = r >> 9;            // ct*KS + ks
    const int ks = t2 % KS, ct = t2 / KS;
    const int c = ct * 16 + (lane & 15);
    const int k = ks * 32 + (lane >> 4) * 8 + j;
    float v = W[(size_t)l * per + (size_t)k * C + c] * S[l * C + c];
    Wp[idx] = f2bf(v);
}

// One fused prep kernel: all 6 weight preps + triangular table.
constexpr int SEG0 = L * 128 * 256;   // 98304
constexpr int SEG1 = L * 256 * 256;   // 196608
constexpr int SEG2 = L * 256 * 128;   // 98304
constexpr int SEG3 = L * 128 * 128;   // 49152
constexpr int SEG4 = L * 384 * 256;   // 294912
constexpr int SEG5 = L * 256 * 128;   // 98304
constexpr int PREP_TOTAL = SEG0 + SEG1 + SEG2 + SEG3 + SEG4 + SEG5 + NTRI;

__global__ void k_prep_all(
    const float* __restrict__ eW0, const float* __restrict__ eS0, unsigned short* __restrict__ w0t,
    const float* __restrict__ eW1, const float* __restrict__ eS1, unsigned short* __restrict__ w1t,
    const float* __restrict__ eW2, const float* __restrict__ eS2, unsigned short* __restrict__ w2t,
    const float* __restrict__ eW3, const float* __restrict__ eS3, unsigned short* __restrict__ w3t,
    const float* __restrict__ nW0, const float* __restrict__ nS0, unsigned short* __restrict__ nw0f,
    const float* __restrict__ nW1, const float* __restrict__ nS1, unsigned short* __restrict__ nw1f,
    unsigned* __restrict__ tab) {
    int idx = blockIdx.x * 256 + threadIdx.x;
    if (idx < SEG0) { wprep_elem(eW0, eS0, w0t, 128, 256, idx); return; }
    idx -= SEG0;
    if (idx < SEG1) { wprep_elem(eW1, eS1, w1t, 256, 256, idx); return; }
    idx -= SEG1;
    if (idx < SEG2) { wprep_elem(eW2, eS2, w2t, 256, 128, idx); return; }
    idx -= SEG2;
    if (idx < SEG3) { wprep_elem(eW3, eS3, w3t, 128, 128, idx); return; }
    idx -= SEG3;
    if (idx < SEG4) { wprep_elem(nW0, nS0, nw0f, 384, 256, idx); return; }
    idx -= SEG4;
    if (idx < SEG5) { wprep_elem(nW1, nS1, nw1f, 256, 128, idx); return; }
    idx -= SEG5;
    if (idx < NTRI) {
        int i, j;
        tri_decode(idx, i, j);
        tab[idx] = (unsigned)((i << 8) | j);
    }
}

// ---------------------------------------------------------------------------
// Kernel A: per (b,m) row — L1-normalize masked edge rows, aggregate node
// features, and build x = [nf | aggr0 | aggr1]  ([B,N,3*NF]). First layer only.
// ---------------------------------------------------------------------------
__global__ void k_aggr_x(const float* __restrict__ nf,
                         const float* __restrict__ ef,
                         float* __restrict__ x) {
    const int b = blockIdx.x / N;
    const int m = blockIdx.x - b * N;
    const int t = threadIdx.x;  // 128 threads

    __shared__ float w0[128], w1[128];

    float e0 = 0.f, e1 = 0.f;
    if (t < N) {
        e0 = ef[((size_t)(b * 2 + 0) * N + m) * N + t];
        e1 = ef[((size_t)(b * 2 + 1) * N + m) * N + t];
        if (t == m) { e0 = 0.f; e1 = 0.f; }
    }
    w0[t] = fabsf(e0);
    w1[t] = fabsf(e1);
    __syncthreads();
    for (int s = 64; s > 0; s >>= 1) {
        if (t < s) { w0[t] += w0[t + s]; w1[t] += w1[t + s]; }
        __syncthreads();
    }
    const float s0 = w0[0];
    const float s1 = w1[0];
    __syncthreads();
    w0[t] = (s0 == 0.f) ? 0.f : e0 / s0;
    w1[t] = (s1 == 0.f) ? 0.f : e1 / s1;
    __syncthreads();

    const float* nfb = nf + (size_t)b * N * NF;
    float a0 = 0.f, a1 = 0.f;
#pragma unroll 4
    for (int n = 0; n < N; ++n) {
        const float v = nfb[(size_t)n * NF + t];
        a0 = fmaf(w0[n], v, a0);
        a1 = fmaf(w1[n], v, a1);
    }
    float* xr = x + (size_t)(b * N + m) * (3 * NF);
    xr[t]          = nfb[(size_t)m * NF + t];
    xr[NF + t]     = a0;
    xr[2 * NF + t] = a1;
}

// ---------------------------------------------------------------------------
// Prefetch a layer's ks=0 B-fragments. ct0 = first n-tile owned by this wave.
// ---------------------------------------------------------------------------
template <int K, int NT>
__device__ __forceinline__ void load_bv0(const unsigned short* __restrict__ Wf,
                                         int lane, int ct0, short8* bv) {
    constexpr int KS = K / 32;
#pragma unroll
    for (int n = 0; n < NT; ++n)
        bv[n] = *(const short8*)(Wf + (((size_t)(ct0 + n) * KS) * 64 + lane) * 8);
}

// ---------------------------------------------------------------------------
// MFMA MLP layer (SWAPPED operands): D = W' x h^T, lane holds 4 consecutive
// output CHANNELS of one row -> packed 8-byte LDS writes.
// Wave owns m-tiles [mbase, mbase+MT) and n-tiles [ct0, ct0+NT).
// in/out swizzled LDS tiles: channel c of row p at byte p*(W*2) + ((2c)^((p&15)<<4))
// Bias folded into accumulator init (MFMA C-in).
// ---------------------------------------------------------------------------
template <int K, int COUT, int NT, int MT>
__device__ __forceinline__ void layer_mfma(const unsigned short* in,
                                           unsigned short* out,
                                           const unsigned short* __restrict__ Wf,
                                           const float* __restrict__ Bb,
                                           int lane, int mbase, int ct0,
                                           const short8* bv0) {
    constexpr int KS = K / 32;
    const int r16 = lane & 15, g = lane >> 4;
    f32x4 acc[MT][NT];
#pragma unroll
    for (int n = 0; n < NT; ++n) {
        const f32x4 binit = *(const f32x4*)(Bb + (ct0 + n) * 16 + g * 4);
#pragma unroll
        for (int m = 0; m < MT; ++m) acc[m][n] = binit;
    }

#pragma unroll
    for (int ks = 0; ks < KS; ++ks) {
        short8 av[MT];
        const int abyte = (ks * 64 + g * 16) ^ (r16 << 4);
#pragma unroll
        for (int m = 0; m < MT; ++m) {
            const int p = (mbase + m) * 16 + r16;
            av[m] = *(const short8*)((const char*)in + p * (K * 2) + abyte);
        }
        short8 bv[NT];
#pragma unroll
        for (int n = 0; n < NT; ++n) {
            if (ks == 0) bv[n] = bv0[n];
            else bv[n] = *(const short8*)(Wf + (((size_t)(ct0 + n) * KS + ks) * 64 + lane) * 8);
        }
#pragma unroll
        for (int m = 0; m < MT; ++m)
#pragma unroll
            for (int n = 0; n < NT; ++n)
                acc[m][n] = __builtin_amdgcn_mfma_f32_16x16x32_bf16(
                    bv[n], av[m], acc[m][n], 0, 0, 0);
    }
#pragma unroll
    for (int n = 0; n < NT; ++n) {
        const int c0 = (ct0 + n) * 16 + g * 4;
#pragma unroll
        for (int m = 0; m < MT; ++m) {
            const int p = (mbase + m) * 16 + r16;
            float v0 = acc[m][n][0]; v0 = fmaxf(v0, ALPHA * v0);
            float v1 = acc[m][n][1]; v1 = fmaxf(v1, ALPHA * v1);
            float v2 = acc[m][n][2]; v2 = fmaxf(v2, ALPHA * v2);
            float v3 = acc[m][n][3]; v3 = fmaxf(v3, ALPHA * v3);
            uint2 w;
            w.x = cvt_pk(v0, v1);
            w.y = cvt_pk(v2, v3);
            const int byte = (c0 * 2) ^ (r16 << 4);
            *(uint2*)((char*)out + p * (COUT * 2) + byte) = w;
        }
    }
}

// ---------------------------------------------------------------------------
// Final pair-MLP layer (COUT=128) with the sim dot product FUSED into the
// epilogue: lane dots its channels with Wout, folds g-groups via shfl,
// writes one partial per (wave, local pair) into psum.
// ---------------------------------------------------------------------------
template <int K, int NT, int MT>
__device__ __forceinline__ void layer_mfma_sim(const unsigned short* in,
                                               float* __restrict__ psum,  // [8][MT*16]
                                               const unsigned short* __restrict__ Wf,
                                               const float* __restrict__ Bb,
                                               const float* __restrict__ Wout,
                                               int lane, int mbase, int ct0, int wave,
                                               const short8* bv0) {
    constexpr int KS = K / 32;
    const int r16 = lane & 15, g = lane >> 4;
    f32x4 acc[MT][NT];
#pragma unroll
    for (int n = 0; n < NT; ++n) {
        const f32x4 binit = *(const f32x4*)(Bb + (ct0 + n) * 16 + g * 4);
#pragma unroll
        for (int m = 0; m < MT; ++m) acc[m][n] = binit;
    }

#pragma unroll
    for (int ks = 0; ks < KS; ++ks) {
        short8 av[MT];
        const int abyte = (ks * 64 + g * 16) ^ (r16 << 4);
#pragma unroll
        for (int m = 0; m < MT; ++m) {
            const int p = (mbase + m) * 16 + r16;
            av[m] = *(const short8*)((const char*)in + p * (K * 2) + abyte);
        }
        short8 bv[NT];
#pragma unroll
        for (int n = 0; n < NT; ++n) {
            if (ks == 0) bv[n] = bv0[n];
            else bv[n] = *(const short8*)(Wf + (((size_t)(ct0 + n) * KS + ks) * 64 + lane) * 8);
        }
#pragma unroll
        for (int m = 0; m < MT; ++m)
#pragma unroll
            for (int n = 0; n < NT; ++n)
                acc[m][n] = __builtin_amdgcn_mfma_f32_16x16x32_bf16(
                    bv[n], av[m], acc[m][n], 0, 0, 0);
    }

    float4 w4[NT];
#pragma unroll
    for (int n = 0; n < NT; ++n)
        w4[n] = *(const float4*)(Wout + (ct0 + n) * 16 + g * 4);
#pragma unroll
    for (int m = 0; m < MT; ++m) {
        float part = 0.f;
#pragma unroll
        for (int n = 0; n < NT; ++n) {
            float v0 = acc[m][n][0]; v0 = fmaxf(v0, ALPHA * v0);
            float v1 = acc[m][n][1]; v1 = fmaxf(v1, ALPHA * v1);
            float v2 = acc[m][n][2]; v2 = fmaxf(v2, ALPHA * v2);
            float v3 = acc[m][n][3]; v3 = fmaxf(v3, ALPHA * v3);
            part = fmaf(v0, w4[n].x, part);
            part = fmaf(v1, w4[n].y, part);
            part = fmaf(v2, w4[n].z, part);
            part = fmaf(v3, w4[n].w, part);
        }
        part += __shfl_xor(part, 16);
        part += __shfl_xor(part, 32);
        if (g == 0) psum[wave * (MT * 16) + m * 16 + r16] = part;
    }
}

// ---------------------------------------------------------------------------
// Same MFMA layer but epilogue writes f32 row-major to GLOBAL (node output).
// ---------------------------------------------------------------------------
template <int K, int COUT, int NT, int MT>
__device__ __forceinline__ void layer_mfma_f32out(const unsigned short* in,
                                                  float* __restrict__ outg, int row0,
                                                  const unsigned short* __restrict__ Wf,
                                                  const float* __restrict__ Bb,
                                                  int lane, int mbase, int ct0,
                                                  const short8* bv0) {
    constexpr int KS = K / 32;
    const int r16 = lane & 15, g = lane >> 4;
    f32x4 acc[MT][NT];
#pragma unroll
    for (int n = 0; n < NT; ++n) {
        const f32x4 binit = *(const f32x4*)(Bb + (ct0 + n) * 16 + g * 4);
#pragma unroll
        for (int m = 0; m < MT; ++m) acc[m][n] = binit;
    }

#pragma unroll
    for (int ks = 0; ks < KS; ++ks) {
        short8 av[MT];
        const int abyte = (ks * 64 + g * 16) ^ (r16 << 4);
#pragma unroll
        for (int m = 0; m < MT; ++m) {
            const int p = (mbase + m) * 16 + r16;
            av[m] = *(const short8*)((const char*)in + p * (K * 2) + abyte);
        }
        short8 bv[NT];
#pragma unroll
        for (int n = 0; n < NT; ++n) {
            if (ks == 0) bv[n] = bv0[n];
            else bv[n] = *(const short8*)(Wf + (((size_t)(ct0 + n) * KS + ks) * 64 + lane) * 8);
        }
#pragma unroll
        for (int m = 0; m < MT; ++m)
#pragma unroll
            for (int n = 0; n < NT; ++n)
                acc[m][n] = __builtin_amdgcn_mfma_f32_16x16x32_bf16(
                    bv[n], av[m], acc[m][n], 0, 0, 0);
    }
#pragma unroll
    for (int n = 0; n < NT; ++n) {
        const int c0 = (ct0 + n) * 16 + g * 4;
#pragma unroll
        for (int m = 0; m < MT; ++m) {
            const int p = (mbase + m) * 16 + r16;
            float4 o;
            o.x = acc[m][n][0]; o.x = fmaxf(o.x, ALPHA * o.x);
            o.y = acc[m][n][1]; o.y = fmaxf(o.y, ALPHA * o.y);
            o.z = acc[m][n][2]; o.z = fmaxf(o.z, ALPHA * o.z);
            o.w = acc[m][n][3]; o.w = fmaxf(o.w, ALPHA * o.w);
            *(float4*)(outg + (size_t)(row0 + p) * COUT + c0) = o;
        }
    }
}

// ---------------------------------------------------------------------------
// Node MLP via MFMA: x[3200][384] -> leaky affine 256 -> leaky affine 128 (f32)
// 512 threads = 8 waves (1D, all-M), 32 rows/block (100 blocks). 40 KiB LDS.
// ---------------------------------------------------------------------------
__global__ __launch_bounds__(512, 4) void k_node_mfma(
    const float* __restrict__ x,
    const unsigned short* __restrict__ W0f, const float* __restrict__ B0,
    const unsigned short* __restrict__ W1f, const float* __restrict__ B1,
    float* __restrict__ nf_out) {
    __shared__ unsigned short bufA[RT * 384];  // 24 KiB (K=384 swizzled)
    __shared__ unsigned short bufB[RT * 256];  // 16 KiB
    const int t = threadIdx.x;
    const int lane = t & 63, wave = t >> 6;
    const int row0 = blockIdx.x * RT;

    // Stage x rows as swizzled bf16 (row width 384 ch, 48 chunks of 8)
    {
        const int p = t >> 4, q = t & 15;
        const float* xr = x + (size_t)(row0 + p) * 384;
#pragma unroll
        for (int u = 0; u < 3; ++u) {
            const int q8 = q + u * 16;
            const float4 a0 = *(const float4*)(xr + q8 * 8);
            const float4 a1 = *(const float4*)(xr + q8 * 8 + 4);
            uint4 o;
            o.x = cvt_pk(a0.x, a0.y);
            o.y = cvt_pk(a0.z, a0.w);
            o.z = cvt_pk(a1.x, a1.y);
            o.w = cvt_pk(a1.z, a1.w);
            const int byte = (q8 * 16) ^ ((p & 15) << 4);
            *(uint4*)((char*)bufA + p * 768 + byte) = o;
        }
    }
    short8 bvp[4];
    load_bv0<384, 2>(W0f, lane, wave * 2, bvp);
    __syncthreads();
    layer_mfma<384, 256, 2, 2>(bufA, bufB, W0f, B0, lane, 0, wave * 2, bvp);
    load_bv0<256, 1>(W1f, lane, wave, bvp);
    __syncthreads();
    layer_mfma_f32out<256, 128, 1, 2>(bufB, nf_out, row0, W1f, B1, lane, 0, wave, bvp);
}

// ---------------------------------------------------------------------------
// Kernel C: fused pairwise-difference MLP (bf16 MFMA) over TRIANGULAR pairs.
// 2D wave grid: 2 M-groups x 4 N-waves -> A-fragment LDS reads HALVED vs 1D.
// 512 threads = 8 waves, 64 pairs per block; 64 KiB LDS -> 2 blocks/CU.
// Final layer folds sim dot into epilogue (psum aliases bufA, which is free).
// Writes sim to both (i,j) and (j,i).
// ---------------------------------------------------------------------------
__global__ __launch_bounds__(512, 4) void k_pair_mlp_mfma(
    const float* __restrict__ nf,
    const unsigned short* __restrict__ W0f, const float* __restrict__ Bb0,
    const unsigned short* __restrict__ W1f, const float* __restrict__ Bb1,
    const unsigned short* __restrict__ W2f, const float* __restrict__ Bb2,
    const unsigned short* __restrict__ W3f, const float* __restrict__ Bb3,
    const float* __restrict__ Wout, const float* __restrict__ boutp,
    const unsigned* __restrict__ tab,
    float* __restrict__ sim) {
    __shared__ unsigned short bufA[PT * 256];  // 32 KiB
    __shared__ unsigned short bufB[PT * 256];  // 32 KiB
    const int t = threadIdx.x;
    const int lane = t & 63, wave = t >> 6;
    const int wm = wave >> 2;        // m-group 0..1 (m-tiles {0,1} or {2,3})
    const int wn = wave & 3;         // n-wave 0..3
    const int tile0 = blockIdx.x * PT;

    // Stage h0 = |nf_i - nf_j| into bufA as swizzled bf16 (row width 128ch)
    {
        const int p0 = t >> 4, q = t & 15;   // 8-ch chunk per thread
#pragma unroll
        for (int pp = 0; pp < 2; ++pp) {
            const int p = p0 + pp * 32;
            const int P = tile0 + p;
            const int b = P / NTRI;
            const unsigned ij = tab[P - b * NTRI];
            const int i = ij >> 8, j = ij & 255;
            const float4* fi = (const float4*)(nf + ((size_t)(b * N + i)) * NF + q * 8);
            const float4* fj = (const float4*)(nf + ((size_t)(b * N + j)) * NF + q * 8);
            const float4 a0 = fi[0], a1 = fi[1];
            const float4 c0 = fj[0], c1 = fj[1];
            uint4 o;
            o.x = cvt_pk(fabsf(a0.x - c0.x), fabsf(a0.y - c0.y));
            o.y = cvt_pk(fabsf(a0.z - c0.z), fabsf(a0.w - c0.w));
            o.z = cvt_pk(fabsf(a1.x - c1.x), fabsf(a1.y - c1.y));
            o.w = cvt_pk(fabsf(a1.z - c1.z), fabsf(a1.w - c1.w));
            const int byte = (q * 16) ^ ((p & 15) << 4);
            *(uint4*)((char*)bufA + p * 256 + byte) = o;
        }
    }
    short8 bvp[4];
    load_bv0<128, 4>(W0f, lane, wn * 4, bvp);
    __syncthreads();
    layer_mfma<128, 256, 4, 2>(bufA, bufB, W0f, Bb0, lane, wm * 2, wn * 4, bvp);
    load_bv0<256, 4>(W1f, lane, wn * 4, bvp);
    __syncthreads();
    layer_mfma<256, 256, 4, 2>(bufB, bufA, W1f, Bb1, lane, wm * 2, wn * 4, bvp);
    load_bv0<256, 2>(W2f, lane, wn * 2, bvp);
    __syncthreads();
    layer_mfma<256, 128, 2, 2>(bufA, bufB, W2f, Bb2, lane, wm * 2, wn * 2, bvp);
    load_bv0<128, 2>(W3f, lane, wn * 2, bvp);
    __syncthreads();
    // L4 reads bufB; bufA is free -> psum[8][32] aliases it.
    float* psum = (float*)bufA;
    layer_mfma_sim<128, 2, 2>(bufB, psum, W3f, Bb3, Wout, lane, wm * 2, wn * 2, wave, bvp);
    __syncthreads();

    // final: fold 4 n-wave partials per pair, sigmoid, dual write
    if (t < PT) {
        const int pwm = t >> 5, lp = t & 31;
        float acc = 0.f;
#pragma unroll
        for (int w = 0; w < 4; ++w) acc += psum[(pwm * 4 + w) * 32 + lp];
        const int P = tile0 + t;
        const int b = P / NTRI;
        const unsigned ij = tab[P - b * NTRI];
        const int i = ij >> 8, j = ij & 255;
        const float v = acc + boutp[0];
        const float sv = 1.f / (1.f + expf(-v));
        sim[((size_t)(b * N) + i) * N + j] = sv;
        sim[((size_t)(b * N) + j) * N + i] = sv;
    }
}

// ---------------------------------------------------------------------------
// Kernel D (final layer): edge update given sim (row-local; safe in place)
// ---------------------------------------------------------------------------
__global__ void k_edge_update(const float* __restrict__ ef_in,
                              const float* __restrict__ sim,
                              float* __restrict__ ef_out) {
    const int b = blockIdx.x / N;
    const int i = blockIdx.x - b * N;
    const int t = threadIdx.x;  // 128 threads

    __shared__ float r0[128], r1[128], r2[128], r3[128];

    float e0 = 0.f, e1 = 0.f, s = 0.f;
    if (t < N) {
        e0 = ef_in[((size_t)(b * 2 + 0) * N + i) * N + t];
        e1 = ef_in[((size_t)(b * 2 + 1) * N + i) * N + t];
        if (t == i) { e0 = 0.f; e1 = 0.f; }
        s = sim[(size_t)(b * N + i) * N + t];
    }
    float f0 = e0 * s;
    float f1 = e1 * (1.f - s);
    r0[t] = e0; r1[t] = e1; r2[t] = fabsf(f0); r3[t] = fabsf(f1);
    __syncthreads();
    for (int st = 64; st > 0; st >>= 1) {
        if (t < st) {
            r0[t] += r0[t + st];
            r1[t] += r1[t + st];
            r2[t] += r2[t + st];
            r3[t] += r3[t + st];
        }
        __syncthreads();
    }
    const float m0 = r0[0], m1 = r1[0], n0 = r2[0], n1 = r3[0];
    if (t < N) {
        f0 = (n0 == 0.f) ? 0.f : (f0 / n0) * m0;
        f1 = (n1 == 0.f) ? 0.f : (f1 / n1) * m1;
        if (t == i) f0 += 1.f;
        f0 += 1e-6f;
        f1 += 1e-6f;
        const float inv = 1.f / (f0 + f1);
        ef_out[((size_t)(b * 2 + 0) * N + i) * N + t] = f0 * inv;
        ef_out[((size_t)(b * 2 + 1) * N + i) * N + t] = f1 * inv;
    }
}

// ---------------------------------------------------------------------------
// Fused edge update + NEXT-layer aggregation (layers 0..L-2).
// ---------------------------------------------------------------------------
__global__ void k_edge_aggr(const float* __restrict__ ef_in,
                            const float* __restrict__ sim,
                            const float* __restrict__ nf,     // nf_{l+1}
                            float* __restrict__ ef_out,
                            float* __restrict__ x) {
    const int b = blockIdx.x / N;
    const int i = blockIdx.x - b * N;
    const int t = threadIdx.x;  // 128 threads

    __shared__ float r0[128], r1[128], r2[128], r3[128];
    __shared__ float w0s[128], w1s[128];

    float e0 = 0.f, e1 = 0.f, s = 0.f;
    if (t < N) {
        e0 = ef_in[((size_t)(b * 2 + 0) * N + i) * N + t];
        e1 = ef_in[((size_t)(b * 2 + 1) * N + i) * N + t];
        if (t == i) { e0 = 0.f; e1 = 0.f; }
        s = sim[(size_t)(b * N + i) * N + t];
    }
    float f0 = e0 * s;
    float f1 = e1 * (1.f - s);
    r0[t] = e0; r1[t] = e1; r2[t] = fabsf(f0); r3[t] = fabsf(f1);
    __syncthreads();
    for (int st = 64; st > 0; st >>= 1) {
        if (t < st) {
            r0[t] += r0[t + st];
            r1[t] += r1[t + st];
            r2[t] += r2[t + st];
            r3[t] += r3[t + st];
        }
        __syncthreads();
    }
    const float m0 = r0[0], m1 = r1[0], n0 = r2[0], n1 = r3[0];
    float g0 = 0.f, g1 = 0.f;
    if (t < N) {
        f0 = (n0 == 0.f) ? 0.f : (f0 / n0) * m0;
        f1 = (n1 == 0.f) ? 0.f : (f1 / n1) * m1;
        if (t == i) f0 += 1.f;
        f0 += 1e-6f;
        f1 += 1e-6f;
        const float inv = 1.f / (f0 + f1);
        g0 = f0 * inv;
        g1 = f1 * inv;
        ef_out[((size_t)(b * 2 + 0) * N + i) * N + t] = g0;
        ef_out[((size_t)(b * 2 + 1) * N + i) * N + t] = g1;
    }

    const float a0in = (t < N && t != i) ? g0 : 0.f;
    const float a1in = (t < N && t != i) ? g1 : 0.f;
    __syncthreads();
    r0[t] = fabsf(a0in);
    r1[t] = fabsf(a1in);
    __syncthreads();
    for (int st = 64; st > 0; st >>= 1) {
        if (t < st) { r0[t] += r0[t + st]; r1[t] += r1[t + st]; }
        __syncthreads();
    }
    const float s0 = r0[0], s1 = r1[0];
    __syncthreads();
    w0s[t] = (s0 == 0.f) ? 0.f : a0in / s0;
    w1s[t] = (s1 == 0.f) ? 0.f : a1in / s1;
    __syncthreads();

    const float* nfb = nf + (size_t)b * N * NF;
    float a0 = 0.f, a1 = 0.f;
#pragma unroll 4
    for (int n = 0; n < N; ++n) {
        const float v = nfb[(size_t)n * NF + t];
        a0 = fmaf(w0s[n], v, a0);
        a1 = fmaf(w1s[n], v, a1);
    }
    float* xr = x + (size_t)(b * N + i) * (3 * NF);
    xr[t]          = nfb[(size_t)i * NF + t];
    xr[NF + t]     = a0;
    xr[2 * NF + t] = a1;
}

// ---------------------------------------------------------------------------
extern "C" void kernel_launch(void* const* d_in, const int* in_sizes, int n_in,
                              void* d_out, int out_size, void* d_ws, size_t ws_size,
                              hipStream_t stream) {
    (void)in_sizes; (void)n_in; (void)out_size; (void)ws_size;

    const float* node_feat = (const float*)d_in[0];
    const float* edge_feat = (const float*)d_in[1];
    const float* nW0 = (const float*)d_in[2];
    const float* nS0 = (const float*)d_in[3];
    const float* nB0 = (const float*)d_in[4];
    const float* nW1 = (const float*)d_in[5];
    const float* nS1 = (const float*)d_in[6];
    const float* nB1 = (const float*)d_in[7];
    const float* eW0 = (const float*)d_in[8];
    const float* eS0 = (const float*)d_in[9];
    const float* eB0 = (const float*)d_in[10];
    const float* eW1 = (const float*)d_in[11];
    const float* eS1 = (const float*)d_in[12];
    const float* eB1 = (const float*)d_in[13];
    const float* eW2 = (const float*)d_in[14];
    const float* eS2 = (const float*)d_in[15];
    const float* eB2 = (const float*)d_in[16];
    const float* eW3 = (const float*)d_in[17];
    const float* eS3 = (const float*)d_in[18];
    const float* eB3 = (const float*)d_in[19];
    const float* eWout = (const float*)d_in[20];
    const float* eBout = (const float*)d_in[21];

    float* ws     = (float*)d_ws;
    float* nf_a   = ws;                               // B*N*NF
    float* nf_b   = nf_a + (size_t)B * N * NF;        // B*N*NF
    float* xbuf   = nf_b + (size_t)B * N * NF;        // B*N*3*NF
    float* ef_ws  = xbuf + (size_t)B * N * 3 * NF;    // B*2*N*N
    float* simbuf = ef_ws + (size_t)B * 2 * N * N;    // B*N*N
    unsigned short* w0t = (unsigned short*)(simbuf + (size_t)B * N * N);
    unsigned short* w1t = w0t + (size_t)L * 256 * 128;   // fragment-ordered
    unsigned short* w2t = w1t + (size_t)L * 256 * 256;
    unsigned short* w3t = w2t + (size_t)L * 128 * 256;
    unsigned short* nw0f = w3t + (size_t)L * 128 * 128;  // [L][256][384]
    unsigned short* nw1f = nw0f + (size_t)L * 256 * 384; // [L][128][256]
    unsigned* tab = (unsigned*)(nw1f + (size_t)L * 128 * 256);  // NTRI entries
    // total ws ~15 MB

    // --- single fused prep: 6 weight preps + tri table ---
    k_prep_all<<<(PREP_TOTAL + 255) / 256, 256, 0, stream>>>(
        eW0, eS0, w0t, eW1, eS1, w1t, eW2, eS2, w2t, eW3, eS3, w3t,
        nW0, nS0, nw0f, nW1, nS1, nw1f, tab);

    const float* ef_cur = edge_feat;
    float* nf_next_buf[3] = {nf_a, nf_b, nf_a};

    // initial aggregation (layer 0 inputs)
    k_aggr_x<<<B * N, 128, 0, stream>>>(node_feat, edge_feat, xbuf);

    for (int l = 0; l < L; ++l) {
        // ---- node MLP via MFMA ----
        k_node_mfma<<<B * N / RT, 512, 0, stream>>>(
            xbuf,
            nw0f + (size_t)l * 256 * 384, nB0 + l * 2 * NF,
            nw1f + (size_t)l * 128 * 256, nB1 + l * NF,
            nf_next_buf[l]);
        const float* nf_cur = nf_next_buf[l];

        // ---- pairwise MLP via MFMA (triangular pairs, 2Mx4N wave grid) ----
        k_pair_mlp_mfma<<<NPAIR_TRI / PT, 512, 0, stream>>>(
            nf_cur,
            w0t + (size_t)l * 256 * 128, eB0 + l * 256,
            w1t + (size_t)l * 256 * 256, eB1 + l * 256,
            w2t + (size_t)l * 128 * 256, eB2 + l * 128,
            w3t + (size_t)l * 128 * 128, eB3 + l * 128,
            eWout + (size_t)l * 128, eBout + l, tab, simbuf);

        if (l < L - 1) {
            k_edge_aggr<<<B * N, 128, 0, stream>>>(
                ef_cur, simbuf, nf_cur, ef_ws, xbuf);
            ef_cur = ef_ws;
        } else {
            k_edge_update<<<B * N, 128, 0, stream>>>(ef_cur, simbuf, (float*)d_out);
        }
    }
}

// Round 16
// 229.389 us; speedup vs baseline: 1.1692x; 1.1692x over previous
//
#include <hip/hip_runtime.h>
#include <math.h>

#define ALPHA 0.3f

constexpr int B  = 32;
constexpr int N  = 100;
constexpr int NF = 128;
constexpr int L  = 3;
constexpr int NN = N * N;            // 10000
constexpr int NTRI = N * (N + 1) / 2;        // 5050 pairs i<=j
constexpr int NPAIR_TRI = B * NTRI;          // 161600
constexpr int PT = 80;               // pairs per block in the fused MFMA MLP
constexpr int RT = 32;               // rows per block in the node MFMA MLP

typedef __attribute__((ext_vector_type(8))) short short8;
typedef __attribute__((ext_vector_type(4))) float f32x4;

__device__ __forceinline__ unsigned short f2bf(float x) {
    union { float f; unsigned u; } v; v.f = x;
    unsigned r = v.u + 0x7FFF + ((v.u >> 16) & 1);  // RNE
    return (unsigned short)(r >> 16);
}
__device__ __forceinline__ float bf2f(unsigned short h) {
    union { unsigned u; float f; } v; v.u = ((unsigned)h) << 16;
    return v.f;
}
// packed f32x2 -> bf16x2 (RNE, same rounding as f2bf)
__device__ __forceinline__ unsigned cvt_pk(float lo, float hi) {
    unsigned r;
    asm("v_cvt_pk_bf16_f32 %0, %1, %2" : "=v"(r) : "v"(lo), "v"(hi));
    return r;
}

// triangular decode: t in [0,5050) -> (i,j), j>=i (used once in table prep)
__device__ __forceinline__ void tri_decode(int t, int& io, int& jo) {
    int ii = (int)((201.0f - sqrtf(40401.0f - 8.0f * (float)t)) * 0.5f);
    ii = max(0, min(99, ii));
    while (ii > 0 && ii * (201 - ii) / 2 > t) --ii;
    while ((ii + 1) * (200 - ii) / 2 <= t) ++ii;
    io = ii;
    jo = ii + (t - ii * (201 - ii) / 2);
}

// ---------------------------------------------------------------------------
// Weight prep element, MFMA-fragment order (16x16x32), generic K,C:
// Wp[((l*CT+ct)*KS+ks)*64 + lane][8] = W[l][ks*32+(lane>>4)*8+j][ct*16+(lane&15)] * S
// ---------------------------------------------------------------------------
__device__ __forceinline__ void wprep_elem(const float* __restrict__ W,
                                           const float* __restrict__ S,
                                           unsigned short* __restrict__ Wp,
                                           int K, int C, int idx) {
    const int per = K * C;
    const int l = idx / per, r = idx - l * per;
    const int KS = K / 32;
    const int j    = r & 7;
    const int lane = (r >> 3) & 63;
    const int t2   = r >> 9;            // ct*KS + ks
    const int ks = t2 % KS, ct = t2 / KS;
    const int c = ct * 16 + (lane & 15);
    const int k = ks * 32 + (lane >> 4) * 8 + j;
    float v = W[(size_t)l * per + (size_t)k * C + c] * S[l * C + c];
    Wp[idx] = f2bf(v);
}

// One fused prep kernel: all 6 weight preps + triangular table.
constexpr int SEG0 = L * 128 * 256;   // 98304
constexpr int SEG1 = L * 256 * 256;   // 196608
constexpr int SEG2 = L * 256 * 128;   // 98304
constexpr int SEG3 = L * 128 * 128;   // 49152
constexpr int SEG4 = L * 384 * 256;   // 294912
constexpr int SEG5 = L * 256 * 128;   // 98304
constexpr int PREP_TOTAL = SEG0 + SEG1 + SEG2 + SEG3 + SEG4 + SEG5 + NTRI;

__global__ void k_prep_all(
    const float* __restrict__ eW0, const float* __restrict__ eS0, unsigned short* __restrict__ w0t,
    const float* __restrict__ eW1, const float* __restrict__ eS1, unsigned short* __restrict__ w1t,
    const float* __restrict__ eW2, const float* __restrict__ eS2, unsigned short* __restrict__ w2t,
    const float* __restrict__ eW3, const float* __restrict__ eS3, unsigned short* __restrict__ w3t,
    const float* __restrict__ nW0, const float* __restrict__ nS0, unsigned short* __restrict__ nw0f,
    const float* __restrict__ nW1, const float* __restrict__ nS1, unsigned short* __restrict__ nw1f,
    unsigned* __restrict__ tab) {
    int idx = blockIdx.x * 256 + threadIdx.x;
    if (idx < SEG0) { wprep_elem(eW0, eS0, w0t, 128, 256, idx); return; }
    idx -= SEG0;
    if (idx < SEG1) { wprep_elem(eW1, eS1, w1t, 256, 256, idx); return; }
    idx -= SEG1;
    if (idx < SEG2) { wprep_elem(eW2, eS2, w2t, 256, 128, idx); return; }
    idx -= SEG2;
    if (idx < SEG3) { wprep_elem(eW3, eS3, w3t, 128, 128, idx); return; }
    idx -= SEG3;
    if (idx < SEG4) { wprep_elem(nW0, nS0, nw0f, 384, 256, idx); return; }
    idx -= SEG4;
    if (idx < SEG5) { wprep_elem(nW1, nS1, nw1f, 256, 128, idx); return; }
    idx -= SEG5;
    if (idx < NTRI) {
        int i, j;
        tri_decode(idx, i, j);
        tab[idx] = (unsigned)((i << 8) | j);
    }
}

// ---------------------------------------------------------------------------
// Kernel A: per (b,m) row — L1-normalize masked edge rows, aggregate node
// features, and build x = [nf | aggr0 | aggr1]  ([B,N,3*NF]). First layer only.
// ---------------------------------------------------------------------------
__global__ void k_aggr_x(const float* __restrict__ nf,
                         const float* __restrict__ ef,
                         float* __restrict__ x) {
    const int b = blockIdx.x / N;
    const int m = blockIdx.x - b * N;
    const int t = threadIdx.x;  // 128 threads

    __shared__ float w0[128], w1[128];

    float e0 = 0.f, e1 = 0.f;
    if (t < N) {
        e0 = ef[((size_t)(b * 2 + 0) * N + m) * N + t];
        e1 = ef[((size_t)(b * 2 + 1) * N + m) * N + t];
        if (t == m) { e0 = 0.f; e1 = 0.f; }
    }
    w0[t] = fabsf(e0);
    w1[t] = fabsf(e1);
    __syncthreads();
    for (int s = 64; s > 0; s >>= 1) {
        if (t < s) { w0[t] += w0[t + s]; w1[t] += w1[t + s]; }
        __syncthreads();
    }
    const float s0 = w0[0];
    const float s1 = w1[0];
    __syncthreads();
    w0[t] = (s0 == 0.f) ? 0.f : e0 / s0;
    w1[t] = (s1 == 0.f) ? 0.f : e1 / s1;
    __syncthreads();

    const float* nfb = nf + (size_t)b * N * NF;
    float a0 = 0.f, a1 = 0.f;
#pragma unroll 4
    for (int n = 0; n < N; ++n) {
        const float v = nfb[(size_t)n * NF + t];
        a0 = fmaf(w0[n], v, a0);
        a1 = fmaf(w1[n], v, a1);
    }
    float* xr = x + (size_t)(b * N + m) * (3 * NF);
    xr[t]          = nfb[(size_t)m * NF + t];
    xr[NF + t]     = a0;
    xr[2 * NF + t] = a1;
}

// ---------------------------------------------------------------------------
// Prefetch a layer's ks=0 B-fragments (issued before the preceding barrier).
// ---------------------------------------------------------------------------
template <int K, int NT>
__device__ __forceinline__ void load_bv0(const unsigned short* __restrict__ Wf,
                                         int lane, int wave, short8* bv) {
    constexpr int KS = K / 32;
#pragma unroll
    for (int n = 0; n < NT; ++n)
        bv[n] = *(const short8*)(Wf + (((size_t)(wave * NT + n) * KS) * 64 + lane) * 8);
}

// ---------------------------------------------------------------------------
// MFMA MLP layer (SWAPPED operands): D = W' x h^T, lane holds 4 consecutive
// output CHANNELS of one row -> packed 8-byte LDS writes.
// in/out swizzled LDS tiles: channel c of row p at byte p*(W*2) + ((2c)^((p&15)<<4))
// Bias folded into accumulator init (MFMA C-in).
// ---------------------------------------------------------------------------
template <int K, int COUT, int NT, int MT>
__device__ __forceinline__ void layer_mfma(const unsigned short* in,
                                           unsigned short* out,
                                           const unsigned short* __restrict__ Wf,
                                           const float* __restrict__ Bb,
                                           int lane, int wave, const short8* bv0) {
    constexpr int KS = K / 32;
    const int r16 = lane & 15, g = lane >> 4;
    f32x4 acc[MT][NT];
#pragma unroll
    for (int n = 0; n < NT; ++n) {
        const f32x4 binit = *(const f32x4*)(Bb + (wave * NT + n) * 16 + g * 4);
#pragma unroll
        for (int m = 0; m < MT; ++m) acc[m][n] = binit;
    }

#pragma unroll
    for (int ks = 0; ks < KS; ++ks) {
        short8 av[MT];
        const int abyte = (ks * 64 + g * 16) ^ (r16 << 4);
#pragma unroll
        for (int m = 0; m < MT; ++m) {
            const int p = m * 16 + r16;
            av[m] = *(const short8*)((const char*)in + p * (K * 2) + abyte);
        }
        short8 bv[NT];
#pragma unroll
        for (int n = 0; n < NT; ++n) {
            if (ks == 0) bv[n] = bv0[n];
            else bv[n] = *(const short8*)(Wf + (((size_t)(wave * NT + n) * KS + ks) * 64 + lane) * 8);
        }
#pragma unroll
        for (int m = 0; m < MT; ++m)
#pragma unroll
            for (int n = 0; n < NT; ++n)
                acc[m][n] = __builtin_amdgcn_mfma_f32_16x16x32_bf16(
                    bv[n], av[m], acc[m][n], 0, 0, 0);
    }
#pragma unroll
    for (int n = 0; n < NT; ++n) {
        const int c0 = wave * NT * 16 + n * 16 + g * 4;
#pragma unroll
        for (int m = 0; m < MT; ++m) {
            const int p = m * 16 + r16;
            float v0 = acc[m][n][0]; v0 = fmaxf(v0, ALPHA * v0);
            float v1 = acc[m][n][1]; v1 = fmaxf(v1, ALPHA * v1);
            float v2 = acc[m][n][2]; v2 = fmaxf(v2, ALPHA * v2);
            float v3 = acc[m][n][3]; v3 = fmaxf(v3, ALPHA * v3);
            uint2 w;
            w.x = cvt_pk(v0, v1);
            w.y = cvt_pk(v2, v3);
            const int byte = (c0 * 2) ^ (r16 << 4);
            *(uint2*)((char*)out + p * (COUT * 2) + byte) = w;
        }
    }
}

// ---------------------------------------------------------------------------
// Final pair-MLP layer (COUT=128, NT=1) with the sim dot product FUSED into
// the epilogue: lane dots its 4 f32 channels with Wout, folds g-groups via
// shfl, writes one partial per (wave, pair) into psum (reused bufA space).
// ---------------------------------------------------------------------------
template <int K, int MT>
__device__ __forceinline__ void layer_mfma_sim(const unsigned short* in,
                                               float* __restrict__ psum,  // [8][MT*16]
                                               const unsigned short* __restrict__ Wf,
                                               const float* __restrict__ Bb,
                                               const float* __restrict__ Wout,
                                               int lane, int wave, short8 bv0) {
    constexpr int KS = K / 32;
    const int r16 = lane & 15, g = lane >> 4;
    f32x4 acc[MT];
    {
        const f32x4 binit = *(const f32x4*)(Bb + wave * 16 + g * 4);
#pragma unroll
        for (int m = 0; m < MT; ++m) acc[m] = binit;
    }

#pragma unroll
    for (int ks = 0; ks < KS; ++ks) {
        short8 av[MT];
        const int abyte = (ks * 64 + g * 16) ^ (r16 << 4);
#pragma unroll
        for (int m = 0; m < MT; ++m) {
            const int p = m * 16 + r16;
            av[m] = *(const short8*)((const char*)in + p * (K * 2) + abyte);
        }
        const short8 bv = (ks == 0) ? bv0
            : *(const short8*)(Wf + (((size_t)wave * KS + ks) * 64 + lane) * 8);
#pragma unroll
        for (int m = 0; m < MT; ++m)
            acc[m] = __builtin_amdgcn_mfma_f32_16x16x32_bf16(bv, av[m], acc[m], 0, 0, 0);
    }

    const float4 w4 = *(const float4*)(Wout + wave * 16 + g * 4);
#pragma unroll
    for (int m = 0; m < MT; ++m) {
        float v0 = acc[m][0]; v0 = fmaxf(v0, ALPHA * v0);
        float v1 = acc[m][1]; v1 = fmaxf(v1, ALPHA * v1);
        float v2 = acc[m][2]; v2 = fmaxf(v2, ALPHA * v2);
        float v3 = acc[m][3]; v3 = fmaxf(v3, ALPHA * v3);
        float part = v0 * w4.x;
        part = fmaf(v1, w4.y, part);
        part = fmaf(v2, w4.z, part);
        part = fmaf(v3, w4.w, part);
        part += __shfl_xor(part, 16);
        part += __shfl_xor(part, 32);
        if (g == 0) psum[wave * (MT * 16) + m * 16 + r16] = part;
    }
}

// ---------------------------------------------------------------------------
// Same MFMA layer but epilogue writes f32 row-major to GLOBAL (node output).
// ---------------------------------------------------------------------------
template <int K, int COUT, int NT, int MT>
__device__ __forceinline__ void layer_mfma_f32out(const unsigned short* in,
                                                  float* __restrict__ outg, int row0,
                                                  const unsigned short* __restrict__ Wf,
                                                  const float* __restrict__ Bb,
                                                  int lane, int wave, const short8* bv0) {
    constexpr int KS = K / 32;
    const int r16 = lane & 15, g = lane >> 4;
    f32x4 acc[MT][NT];
#pragma unroll
    for (int n = 0; n < NT; ++n) {
        const f32x4 binit = *(const f32x4*)(Bb + (wave * NT + n) * 16 + g * 4);
#pragma unroll
        for (int m = 0; m < MT; ++m) acc[m][n] = binit;
    }

#pragma unroll
    for (int ks = 0; ks < KS; ++ks) {
        short8 av[MT];
        const int abyte = (ks * 64 + g * 16) ^ (r16 << 4);
#pragma unroll
        for (int m = 0; m < MT; ++m) {
            const int p = m * 16 + r16;
            av[m] = *(const short8*)((const char*)in + p * (K * 2) + abyte);
        }
        short8 bv[NT];
#pragma unroll
        for (int n = 0; n < NT; ++n) {
            if (ks == 0) bv[n] = bv0[n];
            else bv[n] = *(const short8*)(Wf + (((size_t)(wave * NT + n) * KS + ks) * 64 + lane) * 8);
        }
#pragma unroll
        for (int m = 0; m < MT; ++m)
#pragma unroll
            for (int n = 0; n < NT; ++n)
                acc[m][n] = __builtin_amdgcn_mfma_f32_16x16x32_bf16(
                    bv[n], av[m], acc[m][n], 0, 0, 0);
    }
#pragma unroll
    for (int n = 0; n < NT; ++n) {
        const int c0 = (wave * NT + n) * 16 + g * 4;
#pragma unroll
        for (int m = 0; m < MT; ++m) {
            const int p = m * 16 + r16;
            float4 o;
            o.x = acc[m][n][0]; o.x = fmaxf(o.x, ALPHA * o.x);
            o.y = acc[m][n][1]; o.y = fmaxf(o.y, ALPHA * o.y);
            o.z = acc[m][n][2]; o.z = fmaxf(o.z, ALPHA * o.z);
            o.w = acc[m][n][3]; o.w = fmaxf(o.w, ALPHA * o.w);
            *(float4*)(outg + (size_t)(row0 + p) * COUT + c0) = o;
        }
    }
}

// ---------------------------------------------------------------------------
// Node MLP via MFMA: x[3200][384] -> leaky affine 256 -> leaky affine 128 (f32)
// 512 threads = 8 waves, 32 rows/block (100 blocks). 40 KiB LDS.
// ---------------------------------------------------------------------------
__global__ __launch_bounds__(512, 4) void k_node_mfma(
    const float* __restrict__ x,
    const unsigned short* __restrict__ W0f, const float* __restrict__ B0,
    const unsigned short* __restrict__ W1f, const float* __restrict__ B1,
    float* __restrict__ nf_out) {
    __shared__ unsigned short bufA[RT * 384];  // 24 KiB (K=384 swizzled)
    __shared__ unsigned short bufB[RT * 256];  // 16 KiB
    const int t = threadIdx.x;
    const int lane = t & 63, wave = t >> 6;
    const int row0 = blockIdx.x * RT;

    // Stage x rows as swizzled bf16 (row width 384 ch, 48 chunks of 8)
    {
        const int p = t >> 4, q = t & 15;
        const float* xr = x + (size_t)(row0 + p) * 384;
#pragma unroll
        for (int u = 0; u < 3; ++u) {
            const int q8 = q + u * 16;
            const float4 a0 = *(const float4*)(xr + q8 * 8);
            const float4 a1 = *(const float4*)(xr + q8 * 8 + 4);
            uint4 o;
            o.x = cvt_pk(a0.x, a0.y);
            o.y = cvt_pk(a0.z, a0.w);
            o.z = cvt_pk(a1.x, a1.y);
            o.w = cvt_pk(a1.z, a1.w);
            const int byte = (q8 * 16) ^ ((p & 15) << 4);
            *(uint4*)((char*)bufA + p * 768 + byte) = o;
        }
    }
    short8 bvp[2];
    load_bv0<384, 2>(W0f, lane, wave, bvp);
    __syncthreads();
    layer_mfma<384, 256, 2, 2>(bufA, bufB, W0f, B0, lane, wave, bvp);
    load_bv0<256, 1>(W1f, lane, wave, bvp);
    __syncthreads();
    layer_mfma_f32out<256, 128, 1, 2>(bufB, nf_out, row0, W1f, B1, lane, wave, bvp);
}

// ---------------------------------------------------------------------------
// Kernel C: fused pairwise-difference MLP (bf16 MFMA) over TRIANGULAR pairs
// (sim symmetric). (i,j) from precomputed table (L2-resident, 20 KB).
// 512 threads = 8 waves, 80 pairs per block; 80 KiB LDS -> 2 blocks/CU.
// Final layer folds sim dot into epilogue (psum aliases bufA, which is free).
// Writes sim to both (i,j) and (j,i).
// ---------------------------------------------------------------------------
__global__ __launch_bounds__(512, 4) void k_pair_mlp_mfma(
    const float* __restrict__ nf,
    const unsigned short* __restrict__ W0f, const float* __restrict__ Bb0,
    const unsigned short* __restrict__ W1f, const float* __restrict__ Bb1,
    const unsigned short* __restrict__ W2f, const float* __restrict__ Bb2,
    const unsigned short* __restrict__ W3f, const float* __restrict__ Bb3,
    const float* __restrict__ Wout, const float* __restrict__ boutp,
    const unsigned* __restrict__ tab,
    float* __restrict__ sim) {
    __shared__ unsigned short bufA[PT * 256];  // 40 KiB
    __shared__ unsigned short bufB[PT * 256];  // 40 KiB
    const int t = threadIdx.x;
    const int lane = t & 63, wave = t >> 6;
    const int tile0 = blockIdx.x * PT;

    // Stage h0 = |nf_i - nf_j| into bufA as swizzled bf16 (row width 128ch)
    {
        const int p0 = t >> 4, q = t & 15;   // 8-ch chunk per thread
        for (int p = p0; p < PT; p += 32) {
            const int P = tile0 + p;
            const int b = P / NTRI;
            const unsigned ij = tab[P - b * NTRI];
            const int i = ij >> 8, j = ij & 255;
            const float4* fi = (const float4*)(nf + ((size_t)(b * N + i)) * NF + q * 8);
            const float4* fj = (const float4*)(nf + ((size_t)(b * N + j)) * NF + q * 8);
            const float4 a0 = fi[0], a1 = fi[1];
            const float4 c0 = fj[0], c1 = fj[1];
            uint4 o;
            o.x = cvt_pk(fabsf(a0.x - c0.x), fabsf(a0.y - c0.y));
            o.y = cvt_pk(fabsf(a0.z - c0.z), fabsf(a0.w - c0.w));
            o.z = cvt_pk(fabsf(a1.x - c1.x), fabsf(a1.y - c1.y));
            o.w = cvt_pk(fabsf(a1.z - c1.z), fabsf(a1.w - c1.w));
            const int byte = (q * 16) ^ ((p & 15) << 4);
            *(uint4*)((char*)bufA + p * 256 + byte) = o;
        }
    }
    short8 bvp[2];
    load_bv0<128, 2>(W0f, lane, wave, bvp);
    __syncthreads();
    layer_mfma<128, 256, 2, 5>(bufA, bufB, W0f, Bb0, lane, wave, bvp);
    load_bv0<256, 2>(W1f, lane, wave, bvp);
    __syncthreads();
    layer_mfma<256, 256, 2, 5>(bufB, bufA, W1f, Bb1, lane, wave, bvp);
    load_bv0<256, 1>(W2f, lane, wave, bvp);
    __syncthreads();
    layer_mfma<256, 128, 1, 5>(bufA, bufB, W2f, Bb2, lane, wave, bvp);
    load_bv0<128, 1>(W3f, lane, wave, bvp);
    __syncthreads();
    // L4 reads bufB; bufA is free -> psum[8][80] aliases it.
    float* psum = (float*)bufA;
    layer_mfma_sim<128, 5>(bufB, psum, W3f, Bb3, Wout, lane, wave, bvp[0]);
    __syncthreads();

    // final: fold 8 wave-partials per pair, sigmoid, dual write
    if (t < PT) {
        float acc = 0.f;
#pragma unroll
        for (int w = 0; w < 8; ++w) acc += psum[w * PT + t];
        const int P = tile0 + t;
        const int b = P / NTRI;
        const unsigned ij = tab[P - b * NTRI];
        const int i = ij >> 8, j = ij & 255;
        const float v = acc + boutp[0];
        const float sv = 1.f / (1.f + expf(-v));
        sim[((size_t)(b * N) + i) * N + j] = sv;
        sim[((size_t)(b * N) + j) * N + i] = sv;
    }
}

// ---------------------------------------------------------------------------
// Kernel D (final layer): edge update given sim (row-local; safe in place)
// ---------------------------------------------------------------------------
__global__ void k_edge_update(const float* __restrict__ ef_in,
                              const float* __restrict__ sim,
                              float* __restrict__ ef_out) {
    const int b = blockIdx.x / N;
    const int i = blockIdx.x - b * N;
    const int t = threadIdx.x;  // 128 threads

    __shared__ float r0[128], r1[128], r2[128], r3[128];

    float e0 = 0.f, e1 = 0.f, s = 0.f;
    if (t < N) {
        e0 = ef_in[((size_t)(b * 2 + 0) * N + i) * N + t];
        e1 = ef_in[((size_t)(b * 2 + 1) * N + i) * N + t];
        if (t == i) { e0 = 0.f; e1 = 0.f; }
        s = sim[(size_t)(b * N + i) * N + t];
    }
    float f0 = e0 * s;
    float f1 = e1 * (1.f - s);
    r0[t] = e0; r1[t] = e1; r2[t] = fabsf(f0); r3[t] = fabsf(f1);
    __syncthreads();
    for (int st = 64; st > 0; st >>= 1) {
        if (t < st) {
            r0[t] += r0[t + st];
            r1[t] += r1[t + st];
            r2[t] += r2[t + st];
            r3[t] += r3[t + st];
        }
        __syncthreads();
    }
    const float m0 = r0[0], m1 = r1[0], n0 = r2[0], n1 = r3[0];
    if (t < N) {
        f0 = (n0 == 0.f) ? 0.f : (f0 / n0) * m0;
        f1 = (n1 == 0.f) ? 0.f : (f1 / n1) * m1;
        if (t == i) f0 += 1.f;
        f0 += 1e-6f;
        f1 += 1e-6f;
        const float inv = 1.f / (f0 + f1);
        ef_out[((size_t)(b * 2 + 0) * N + i) * N + t] = f0 * inv;
        ef_out[((size_t)(b * 2 + 1) * N + i) * N + t] = f1 * inv;
    }
}

// ---------------------------------------------------------------------------
// Fused edge update + NEXT-layer aggregation (layers 0..L-2).
// ---------------------------------------------------------------------------
__global__ void k_edge_aggr(const float* __restrict__ ef_in,
                            const float* __restrict__ sim,
                            const float* __restrict__ nf,     // nf_{l+1}
                            float* __restrict__ ef_out,
                            float* __restrict__ x) {
    const int b = blockIdx.x / N;
    const int i = blockIdx.x - b * N;
    const int t = threadIdx.x;  // 128 threads

    __shared__ float r0[128], r1[128], r2[128], r3[128];
    __shared__ float w0s[128], w1s[128];

    float e0 = 0.f, e1 = 0.f, s = 0.f;
    if (t < N) {
        e0 = ef_in[((size_t)(b * 2 + 0) * N + i) * N + t];
        e1 = ef_in[((size_t)(b * 2 + 1) * N + i) * N + t];
        if (t == i) { e0 = 0.f; e1 = 0.f; }
        s = sim[(size_t)(b * N + i) * N + t];
    }
    float f0 = e0 * s;
    float f1 = e1 * (1.f - s);
    r0[t] = e0; r1[t] = e1; r2[t] = fabsf(f0); r3[t] = fabsf(f1);
    __syncthreads();
    for (int st = 64; st > 0; st >>= 1) {
        if (t < st) {
            r0[t] += r0[t + st];
            r1[t] += r1[t + st];
            r2[t] += r2[t + st];
            r3[t] += r3[t + st];
        }
        __syncthreads();
    }
    const float m0 = r0[0], m1 = r1[0], n0 = r2[0], n1 = r3[0];
    float g0 = 0.f, g1 = 0.f;
    if (t < N) {
        f0 = (n0 == 0.f) ? 0.f : (f0 / n0) * m0;
        f1 = (n1 == 0.f) ? 0.f : (f1 / n1) * m1;
        if (t == i) f0 += 1.f;
        f0 += 1e-6f;
        f1 += 1e-6f;
        const float inv = 1.f / (f0 + f1);
        g0 = f0 * inv;
        g1 = f1 * inv;
        ef_out[((size_t)(b * 2 + 0) * N + i) * N + t] = g0;
        ef_out[((size_t)(b * 2 + 1) * N + i) * N + t] = g1;
    }

    const float a0in = (t < N && t != i) ? g0 : 0.f;
    const float a1in = (t < N && t != i) ? g1 : 0.f;
    __syncthreads();
    r0[t] = fabsf(a0in);
    r1[t] = fabsf(a1in);
    __syncthreads();
    for (int st = 64; st > 0; st >>= 1) {
        if (t < st) { r0[t] += r0[t + st]; r1[t] += r1[t + st]; }
        __syncthreads();
    }
    const float s0 = r0[0], s1 = r1[0];
    __syncthreads();
    w0s[t] = (s0 == 0.f) ? 0.f : a0in / s0;
    w1s[t] = (s1 == 0.f) ? 0.f : a1in / s1;
    __syncthreads();

    const float* nfb = nf + (size_t)b * N * NF;
    float a0 = 0.f, a1 = 0.f;
#pragma unroll 4
    for (int n = 0; n < N; ++n) {
        const float v = nfb[(size_t)n * NF + t];
        a0 = fmaf(w0s[n], v, a0);
        a1 = fmaf(w1s[n], v, a1);
    }
    float* xr = x + (size_t)(b * N + i) * (3 * NF);
    xr[t]          = nfb[(size_t)i * NF + t];
    xr[NF + t]     = a0;
    xr[2 * NF + t] = a1;
}

// ---------------------------------------------------------------------------
extern "C" void kernel_launch(void* const* d_in, const int* in_sizes, int n_in,
                              void* d_out, int out_size, void* d_ws, size_t ws_size,
                              hipStream_t stream) {
    (void)in_sizes; (void)n_in; (void)out_size; (void)ws_size;

    const float* node_feat = (const float*)d_in[0];
    const float* edge_feat = (const float*)d_in[1];
    const float* nW0 = (const float*)d_in[2];
    const float* nS0 = (const float*)d_in[3];
    const float* nB0 = (const float*)d_in[4];
    const float* nW1 = (const float*)d_in[5];
    const float* nS1 = (const float*)d_in[6];
    const float* nB1 = (const float*)d_in[7];
    const float* eW0 = (const float*)d_in[8];
    const float* eS0 = (const float*)d_in[9];
    const float* eB0 = (const float*)d_in[10];
    const float* eW1 = (const float*)d_in[11];
    const float* eS1 = (const float*)d_in[12];
    const float* eB1 = (const float*)d_in[13];
    const float* eW2 = (const float*)d_in[14];
    const float* eS2 = (const float*)d_in[15];
    const float* eB2 = (const float*)d_in[16];
    const float* eW3 = (const float*)d_in[17];
    const float* eS3 = (const float*)d_in[18];
    const float* eB3 = (const float*)d_in[19];
    const float* eWout = (const float*)d_in[20];
    const float* eBout = (const float*)d_in[21];

    float* ws     = (float*)d_ws;
    float* nf_a   = ws;                               // B*N*NF
    float* nf_b   = nf_a + (size_t)B * N * NF;        // B*N*NF
    float* xbuf   = nf_b + (size_t)B * N * NF;        // B*N*3*NF
    float* ef_ws  = xbuf + (size_t)B * N * 3 * NF;    // B*2*N*N
    float* simbuf = ef_ws + (size_t)B * 2 * N * N;    // B*N*N
    unsigned short* w0t = (unsigned short*)(simbuf + (size_t)B * N * N);
    unsigned short* w1t = w0t + (size_t)L * 256 * 128;   // fragment-ordered
    unsigned short* w2t = w1t + (size_t)L * 256 * 256;
    unsigned short* w3t = w2t + (size_t)L * 128 * 256;
    unsigned short* nw0f = w3t + (size_t)L * 128 * 128;  // [L][256][384]
    unsigned short* nw1f = nw0f + (size_t)L * 256 * 384; // [L][128][256]
    unsigned* tab = (unsigned*)(nw1f + (size_t)L * 128 * 256);  // NTRI entries
    // total ws ~15 MB

    // --- single fused prep: 6 weight preps + tri table ---
    k_prep_all<<<(PREP_TOTAL + 255) / 256, 256, 0, stream>>>(
        eW0, eS0, w0t, eW1, eS1, w1t, eW2, eS2, w2t, eW3, eS3, w3t,
        nW0, nS0, nw0f, nW1, nS1, nw1f, tab);

    const float* ef_cur = edge_feat;
    float* nf_next_buf[3] = {nf_a, nf_b, nf_a};

    // initial aggregation (layer 0 inputs)
    k_aggr_x<<<B * N, 128, 0, stream>>>(node_feat, edge_feat, xbuf);

    for (int l = 0; l < L; ++l) {
        // ---- node MLP via MFMA ----
        k_node_mfma<<<B * N / RT, 512, 0, stream>>>(
            xbuf,
            nw0f + (size_t)l * 256 * 384, nB0 + l * 2 * NF,
            nw1f + (size_t)l * 128 * 256, nB1 + l * NF,
            nf_next_buf[l]);
        const float* nf_cur = nf_next_buf[l];

        // ---- pairwise MLP via MFMA (triangular pairs) ----
        k_pair_mlp_mfma<<<NPAIR_TRI / PT, 512, 0, stream>>>(
            nf_cur,
            w0t + (size_t)l * 256 * 128, eB0 + l * 256,
            w1t + (size_t)l * 256 * 256, eB1 + l * 256,
            w2t + (size_t)l * 128 * 256, eB2 + l * 128,
            w3t + (size_t)l * 128 * 128, eB3 + l * 128,
            eWout + (size_t)l * 128, eBout + l, tab, simbuf);

        if (l < L - 1) {
            k_edge_aggr<<<B * N, 128, 0, stream>>>(
                ef_cur, simbuf, nf_cur, ef_ws, xbuf);
            ef_cur = ef_ws;
        } else {
            k_edge_update<<<B * N, 128, 0, stream>>>(ef_cur, simbuf, (float*)d_out);
        }
    }
}